// Round 1
// baseline (1733.080 us; speedup 1.0000x reference)
//
#include <hip/hip_runtime.h>

// ROSA 1-bit: B=4, T=2048, C=128. One block per (b,c) sequence.
// Diagonal decomposition: lcs(i, i-d) = trailing-run length of match
// indicator on diagonal d. Per-cell packed LDS atomicMax gives
// (max run, most-recent j) per i.

#define TT 2048
#define CC 128
#define NWORDS (TT / 32)   // 64 bit-words per sequence

__global__ __launch_bounds__(256, 2) void rosa_kernel(
    const float* __restrict__ x,
    const float* __restrict__ emb0,
    const float* __restrict__ emb1,
    float* __restrict__ out)
{
    __shared__ unsigned int sbits[NWORDS];
    __shared__ unsigned int sres[TT];

    const int blk = blockIdx.x;
    const int b   = blk >> 7;    // / CC
    const int c   = blk & 127;   // % CC
    const int tid = threadIdx.x;

    for (int w = tid; w < NWORDS; w += 256) sbits[w] = 0u;
    for (int i = tid; i < TT;     i += 256) sres[i]  = 0u;
    __syncthreads();

    // ---- load bits of this sequence: bit(i) = (x[b,i,c] > 0) ----
    const float* xs = x + ((size_t)b * TT) * CC + c;
    for (int i = tid; i < TT; i += 256) {
        float v = xs[(size_t)i * CC];
        if (v > 0.0f) atomicOr(&sbits[i >> 5], 1u << (i & 31));
    }
    __syncthreads();

    // ---- DP: each thread owns 8 diagonals d = 1 + tid + 256k ----
    for (int k = 0; k < 8; ++k) {
        const int d = 1 + tid + (k << 8);
        if (d >= TT) continue;
        const unsigned int dcode = (unsigned int)(2048 - d); // larger = more recent j
        const int dw = d >> 5;
        const int dr = d & 31;
        unsigned int cnt = 0u;

        for (int i0 = d & ~31; i0 < TT; i0 += 32) {
            const int w = i0 >> 5;
            const unsigned int a  = sbits[w];
            const unsigned int W0 = sbits[w - dw];
            const unsigned int W1 = (w - dw >= 1) ? sbits[w - dw - 1] : 0u;
            // bit bb of s = bit(i0+bb-d)
            const unsigned int s = dr ? ((W0 << dr) | (W1 >> (32 - dr))) : W0;
            unsigned int m = ~(a ^ s);              // equality mask
            if (i0 < d) m &= (0xFFFFFFFFu << (d - i0)); // drop i < d

            #pragma unroll
            for (int bb = 0; bb < 32; ++bb) {
                cnt = ((m >> bb) & 1u) ? (cnt + 1u) : 0u;
                if (cnt) atomicMax(&sres[i0 + bb], (cnt << 11) | dcode);
            }
        }
    }
    __syncthreads();

    // ---- decode + write output ----
    const float e0 = emb0[c];
    const float e1 = emb1[c];
    float* os = out + ((size_t)b * TT) * CC + c;
    for (int i = tid; i < TT; i += 256) {
        const unsigned int v = sres[i];
        float val = 0.0f;
        if (v != 0u) {
            const int d   = 2048 - (int)(v & 2047u);
            const int ep1 = i - d + 1;               // e + 1, in [1, i]
            const unsigned int bit = (sbits[ep1 >> 5] >> (ep1 & 31)) & 1u;
            val = bit ? e1 : e0;
        }
        os[(size_t)i * CC] = val;
    }
}

extern "C" void kernel_launch(void* const* d_in, const int* in_sizes, int n_in,
                              void* d_out, int out_size, void* d_ws, size_t ws_size,
                              hipStream_t stream)
{
    const float* x    = (const float*)d_in[0];
    const float* emb0 = (const float*)d_in[1];
    const float* emb1 = (const float*)d_in[2];
    float* out        = (float*)d_out;

    const int B = in_sizes[0] / (TT * CC);   // 4
    rosa_kernel<<<dim3(B * CC), dim3(256), 0, stream>>>(x, emb0, emb1, out);
}

// Round 2
// 369.906 us; speedup vs baseline: 4.6852x; 4.6852x over previous
//
#include <hip/hip_runtime.h>

// ROSA 1-bit, B=4, T=2048, C=128 (512 sequences).
// Round 2: wave-parallel-over-words, serial-over-diagonals. Lane l owns
// bit-word l (32 positions). Per diagonal (wave-uniform scalar), each lane
// builds the match mask, gets the incoming run via a 1-shfl scan fast path,
// and updates per-bit packed maxima (run<<11 | 2048-d) in registers.
// No per-cell LDS atomics (round-1 bottleneck: 5e8 LDS bank-conflict cycles).

#define TT 2048
#define CC 128
#define NW 64            // 32-bit words per sequence
#define NSEQ 512         // B*C
#define NCHUNK 8         // diagonal chunks (blocks) per sequence
#define SBITS_WORDS (NSEQ * NW)            // 32768 u32 = 128 KB
#define RES_WORDS (4 * TT * CC)            // 1 Mi u32 = 4 MB, layout [b][i][c]

// ---------------- kernel 0: pack bits ----------------
// grid: 4 * 64 = 256 blocks, 256 threads. Block = (b, word w). Coalesced x
// reads, LDS byte transpose, 128 threads assemble one u32 word per channel.
__global__ void k_bits(const float* __restrict__ x, unsigned* __restrict__ sbits)
{
    const int b = blockIdx.x >> 6;
    const int w = blockIdx.x & 63;
    const int t = threadIdx.x;
    __shared__ unsigned char sbyt[32 * 132];   // [ii][c], padded row 132

    #pragma unroll
    for (int r = 0; r < 16; ++r) {
        const int e  = t + (r << 8);          // 0..4095
        const int ii = e >> 7;
        const int c  = e & 127;
        const float v = x[((size_t)(b * TT + (w << 5) + ii)) * CC + c];
        sbyt[ii * 132 + c] = (v > 0.0f) ? 1u : 0u;
    }
    __syncthreads();

    if (t < CC) {
        unsigned word = 0u;
        #pragma unroll
        for (int ii = 0; ii < 32; ++ii)
            word |= (unsigned)(sbyt[ii * 132 + t] & 1u) << ii;
        sbits[((b << 7) | t) * NW + w] = word;
    }
}

// ---------------- kernel 1: diagonal DP ----------------
// grid: 512 seq * 8 chunks = 4096 blocks, 256 threads (4 waves).
// Wave v of chunk s handles diagonals d = 1 + 256*s + v + 4*j and +128, j<32.
__global__ __launch_bounds__(256, 4) void k_dp(
    const unsigned* __restrict__ sbits, unsigned* __restrict__ res)
{
    const int blk  = blockIdx.x;
    const int q    = blk >> 3;           // sequence
    const int s    = blk & 7;            // chunk
    const int b    = q >> 7;
    const int c    = q & 127;
    const int lane = threadIdx.x & 63;
    const int wv   = threadIdx.x >> 6;

    __shared__ unsigned pad[NW * 2];          // [0..63]=0, [64+w]=word w
    __shared__ unsigned wres[4][64][33];      // padded per-wave results

    if (threadIdx.x < NW) pad[threadIdx.x] = 0u;
    else if (threadIdx.x < 2 * NW) pad[threadIdx.x] = sbits[q * NW + threadIdx.x - NW];
    __syncthreads();

    const unsigned a = pad[NW + lane];        // this lane's word, lives in a VGPR

    unsigned lmax[32];
    #pragma unroll
    for (int bb = 0; bb < 32; ++bb) lmax[bb] = 0u;

    const int cbase = 1 + (s << 8) + wv;

    for (int j = 0; j < 32; ++j) {
        #pragma unroll
        for (int half = 0; half < 2; ++half) {
            const int d = cbase + (j << 2) + (half << 7);
            if (d > TT - 1) continue;                       // only s=7,wv=3,j=31,half=1
            const int dw = d >> 5;
            const int dr = d & 31;
            const unsigned dcode = (unsigned)(TT - d);

            const unsigned b1 = pad[NW - 1 + lane - dw];
            const unsigned b0 = pad[NW + lane - dw];
            const unsigned sh = dr ? ((b0 << dr) | (b1 >> (32 - dr))) : b0;
            unsigned m = ~(a ^ sh);
            // edge mask: zero lanes below dw, partial at lane==dw
            const unsigned em = (lane > dw) ? 0xFFFFFFFFu
                              : ((lane == dw) ? (0xFFFFFFFFu << dr) : 0u);
            m &= em;

            // incoming run (ones ending at end of previous word)
            unsigned inc;
            const unsigned long long fullmask = __ballot(m == 0xFFFFFFFFu);
            if (fullmask == 0ULL) {
                const unsigned nm = ~m;
                const unsigned lo = (unsigned)__builtin_clz(nm | 1u) + ((nm & 1u) ? 0u : 0u);
                // nm != 0 guaranteed here (no full words); plain clz is safe:
                const unsigned lead = (unsigned)__builtin_clz(nm);
                unsigned p = __shfl_up(lead, 1);
                inc = (lane == 0) ? 0u : p;
                (void)lo;
            } else {
                // general segmented operator scan: f(x) = g*x + cc
                const unsigned nm = ~m;
                unsigned g  = (nm == 0u) ? 1u : 0u;
                unsigned cc = (nm == 0u) ? 32u : (unsigned)__builtin_clz(nm);
                #pragma unroll
                for (int k = 1; k < 64; k <<= 1) {
                    const unsigned gA = __shfl_up(g, k);
                    const unsigned cA = __shfl_up(cc, k);
                    if (lane >= k) { cc += g ? cA : 0u; g &= gA; }
                }
                unsigned p = __shfl_up(cc, 1);
                inc = (lane == 0) ? 0u : p;
            }

            unsigned run = inc;
            #pragma unroll
            for (int bb = 0; bb < 32; ++bb) {
                const unsigned keep = (unsigned)(((int)(m << (31 - bb))) >> 31); // sbfe
                run = (run + 1u) & keep;
                const unsigned pk = (run << 11) | dcode;
                lmax[bb] = lmax[bb] >= pk ? lmax[bb] : pk;
            }
        }
    }

    #pragma unroll
    for (int bb = 0; bb < 32; ++bb) wres[wv][lane][bb] = lmax[bb];
    __syncthreads();

    unsigned* resq = res + ((size_t)b * TT) * CC + c;
    #pragma unroll
    for (int r = 0; r < 8; ++r) {
        const int i = threadIdx.x + (r << 8);
        const int iw = i >> 5, ib = i & 31;
        unsigned v0 = wres[0][iw][ib];
        unsigned v1 = wres[1][iw][ib];
        unsigned v2 = wres[2][iw][ib];
        unsigned v3 = wres[3][iw][ib];
        unsigned v = max(max(v0, v1), max(v2, v3));
        if (v >> 11) atomicMax(&resq[(size_t)i * CC], v);
    }
}

// ---------------- kernel 2: decode ----------------
// thread per output element, flat = ((b*T + i)*C + c). Coalesced res read +
// out write; scattered small sbits read (L2-resident, 128 KB).
__global__ void k_dec(const unsigned* __restrict__ sbits,
                      const unsigned* __restrict__ res,
                      const float* __restrict__ emb0,
                      const float* __restrict__ emb1,
                      float* __restrict__ out)
{
    const int t = blockIdx.x * 256 + threadIdx.x;
    const unsigned v = res[t];
    const int c = t & 127;
    float val = 0.0f;
    if (v >> 11) {
        const int i  = (t >> 7) & (TT - 1);
        const int b  = t >> 18;
        const int d  = TT - (int)(v & 2047u);
        const int e1 = i - d + 1;
        const unsigned bw = sbits[((b << 7) | c) * NW + (e1 >> 5)];
        val = ((bw >> (e1 & 31)) & 1u) ? emb1[c] : emb0[c];
    }
    out[t] = val;
}

extern "C" void kernel_launch(void* const* d_in, const int* in_sizes, int n_in,
                              void* d_out, int out_size, void* d_ws, size_t ws_size,
                              hipStream_t stream)
{
    const float* x    = (const float*)d_in[0];
    const float* emb0 = (const float*)d_in[1];
    const float* emb1 = (const float*)d_in[2];
    float* out        = (float*)d_out;

    unsigned* sbits = (unsigned*)d_ws;                       // 128 KB
    unsigned* res   = (unsigned*)d_ws + SBITS_WORDS;         // 4 MB

    hipMemsetAsync((void*)res, 0, (size_t)RES_WORDS * 4, stream);
    k_bits<<<dim3(4 * 64), dim3(256), 0, stream>>>(x, sbits);
    k_dp<<<dim3(NSEQ * NCHUNK), dim3(256), 0, stream>>>(sbits, res);
    k_dec<<<dim3(RES_WORDS / 256), dim3(256), 0, stream>>>(sbits, res, emb0, emb1, out);
}

// Round 3
// 201.714 us; speedup vs baseline: 8.5918x; 1.8338x over previous
//
#include <hip/hip_runtime.h>

// ROSA 1-bit, B=4, T=2048, C=128 (512 sequences).
// Round 3: i-tiled diagonal DP. Tile k covers i in [256k, 256k+256) (8 words).
// Wave = 8 diagonal-streams x 8 lanes; lane's output word fixed = 8k+(lane&7)
// so per-bit maxima stay in registers. Diagonals below the tile use all 8
// lanes (no masked-lane waste; round-2 wasted ~50%). Boundary incoming runs
// computed by per-stream-head backward scan (expected O(1) words).

#define TT 2048
#define CC 128
#define NW 64
#define NSEQ 512
#define SBITS_WORDS (NSEQ * NW)       // 128 KB
#define RES_WORDS (4 * TT * CC)       // 4 MB, layout [b][i][c]

// ---------------- kernel 0: pack bits (as round 2) ----------------
__global__ void k_bits(const float* __restrict__ x, unsigned* __restrict__ sbits)
{
    const int b = blockIdx.x >> 6;
    const int w = blockIdx.x & 63;
    const int t = threadIdx.x;
    __shared__ unsigned char sbyt[32 * 132];

    #pragma unroll
    for (int r = 0; r < 16; ++r) {
        const int e  = t + (r << 8);
        const int ii = e >> 7;
        const int c  = e & 127;
        const float v = x[((size_t)(b * TT + (w << 5) + ii)) * CC + c];
        sbyt[ii * 132 + c] = (v > 0.0f) ? 1u : 0u;
    }
    __syncthreads();

    if (t < CC) {
        unsigned word = 0u;
        #pragma unroll
        for (int ii = 0; ii < 32; ++ii)
            word |= (unsigned)(sbyt[ii * 132 + t] & 1u) << ii;
        sbits[((b << 7) | t) * NW + w] = word;
    }
}

// ---------------- kernel 1: tiled diagonal DP ----------------
// grid (36, 512): blockIdx.x -> (tile k, diagonal chunk), blockIdx.y = seq.
// Block: 256 thr = 4 waves; covers 256 diagonals = 4 waves x 8 streams x 8 it.
__global__ __launch_bounds__(256, 4) void k_dp2(
    const unsigned* __restrict__ sbits, unsigned* __restrict__ res)
{
    const int u = blockIdx.x;            // 0..35  (triangular (k, chunk))
    const int q = blockIdx.y;            // sequence
    int k = 0;
    #pragma unroll
    for (int kk = 1; kk < 8; ++kk) if (u >= (kk * (kk + 1)) / 2) k = kk;
    const int chunk = u - (k * (k + 1)) / 2;    // 0..k
    const int D0 = 1 + (chunk << 8);            // first diagonal of this block

    const int tid  = threadIdx.x;
    const int lane = tid & 63;
    const int wv   = tid >> 6;
    const int g    = lane >> 3;          // stream in wave
    const int lm   = lane & 7;           // lane within stream
    const int wloc = (k << 3) + lm;      // fixed output word of this lane
    const int kb   = k << 8;             // tile base i = 256k

    __shared__ unsigned pad[128];        // [0..63]=0, [64+w]=word w
    __shared__ unsigned wres[4][8][33];  // padded per-wave results

    if (tid < 64) pad[tid] = 0u;
    else if (tid < 128) pad[tid] = sbits[q * NW + (tid - 64)];
    __syncthreads();

    const unsigned a = pad[64 + wloc];

    unsigned lmax[32];
    #pragma unroll
    for (int bb = 0; bb < 32; ++bb) lmax[bb] = 0u;

    for (int it = 0; it < 8; ++it) {
        const int d  = D0 + (it << 5) + (wv << 3) + g;   // <= 2048
        const int dw = d >> 5;
        const int dr = d & 31;
        const unsigned dcode = (unsigned)(TT - d);        // 0 when d==2048 (em=0 then)

        const int s = wloc - dw;
        const unsigned em = (s > 0) ? 0xFFFFFFFFu
                          : ((s == 0) ? (0xFFFFFFFFu << dr) : 0u);

        const unsigned b0 = pad[64 + s];
        const unsigned b1 = pad[63 + s];
        const unsigned sh = dr ? ((b0 << dr) | (b1 >> (32 - dr))) : b0;
        const unsigned m = (~(a ^ sh)) & em;

        // --- boundary incoming run (head lanes, full diagonals only) ---
        unsigned inc0 = 0u;
        if (lm == 0 && d < kb) {
            int w = (k << 3) - 1;
            while (w >= 0) {
                const int ss = w - dw;
                const unsigned emw = (ss > 0) ? 0xFFFFFFFFu
                                   : ((ss == 0) ? (0xFFFFFFFFu << dr) : 0u);
                const unsigned c0 = pad[64 + ss];
                const unsigned c1 = pad[63 + ss];
                const unsigned shw = dr ? ((c0 << dr) | (c1 >> (32 - dr))) : c0;
                const unsigned mw = (~(pad[64 + w] ^ shw)) & emw;
                const unsigned t2 = (mw == 0xFFFFFFFFu) ? 32u
                                  : (unsigned)__builtin_clz(~mw);
                inc0 += t2;
                if (t2 < 32u) break;
                --w;
            }
        }

        // --- incoming run per lane ---
        unsigned inc;
        const unsigned long long anyfull = __ballot(m == 0xFFFFFFFFu);
        if (anyfull == 0ULL) {
            const unsigned pm = __shfl_up(m, 1);          // pm != ~0 here
            const unsigned lead = (unsigned)__builtin_clz(~pm);
            inc = (lm == 0) ? inc0 : lead;
        } else {
            // segmented (per-octet) operator scan: out = c + g*in
            unsigned gg = (m == 0xFFFFFFFFu) ? 1u : 0u;
            unsigned cc = gg ? 32u : (unsigned)__builtin_clz(~m | 1u);
            // (| 1u guards clz(0) when m==~0; that lane uses cc=32 anyway)
            #pragma unroll
            for (int st = 1; st < 8; st <<= 1) {
                const unsigned gp = __shfl_up(gg, st);
                const unsigned cp = __shfl_up(cc, st);
                if (lm >= st) { cc += gg ? cp : 0u; gg &= gp; }
            }
            const unsigned h0 = __shfl(inc0, lane & ~7);
            const unsigned outl = cc + (gg ? h0 : 0u);
            const unsigned po = __shfl_up(outl, 1);
            inc = (lm == 0) ? inc0 : po;
        }

        // --- per-bit run + packed max ---
        unsigned pkv = (inc << 11) | dcode;
        #pragma unroll
        for (int bb = 0; bb < 32; ++bb) {
            const unsigned keep = (unsigned)(((int)(m << (31 - bb))) >> 31);
            const unsigned t2 = pkv + 2048u;
            pkv = (t2 & keep) | (dcode & ~keep);          // bfi select
            lmax[bb] = lmax[bb] >= pkv ? lmax[bb] : pkv;
        }
    }

    // --- reduce the 8 streams sharing each word (lanes l, l+8, ..., l+56) ---
    #pragma unroll
    for (int bb = 0; bb < 32; ++bb) {
        unsigned v = lmax[bb];
        v = max(v, (unsigned)__shfl_xor((int)v, 8));
        v = max(v, (unsigned)__shfl_xor((int)v, 16));
        v = max(v, (unsigned)__shfl_xor((int)v, 32));
        lmax[bb] = v;
    }
    if (lane < 8) {
        #pragma unroll
        for (int bb = 0; bb < 32; ++bb) wres[wv][lane][bb] = lmax[bb];
    }
    __syncthreads();

    // --- block merge + one global atomic per output ---
    {
        const int lw = tid >> 5, bb = tid & 31;
        const unsigned v = max(max(wres[0][lw][bb], wres[1][lw][bb]),
                               max(wres[2][lw][bb], wres[3][lw][bb]));
        if (v >> 11) {
            const int b = q >> 7, c = q & 127;
            const int i = ((k << 3) + lw) * 32 + bb;
            atomicMax(&res[((size_t)b * TT + i) * CC + c], v);
        }
    }
}

// ---------------- kernel 2: decode (as round 2) ----------------
__global__ void k_dec(const unsigned* __restrict__ sbits,
                      const unsigned* __restrict__ res,
                      const float* __restrict__ emb0,
                      const float* __restrict__ emb1,
                      float* __restrict__ out)
{
    const int t = blockIdx.x * 256 + threadIdx.x;
    const unsigned v = res[t];
    const int c = t & 127;
    float val = 0.0f;
    if (v >> 11) {
        const int i  = (t >> 7) & (TT - 1);
        const int b  = t >> 18;
        const int d  = TT - (int)(v & 2047u);
        const int e1 = i - d + 1;
        const unsigned bw = sbits[((b << 7) | c) * NW + (e1 >> 5)];
        val = ((bw >> (e1 & 31)) & 1u) ? emb1[c] : emb0[c];
    }
    out[t] = val;
}

extern "C" void kernel_launch(void* const* d_in, const int* in_sizes, int n_in,
                              void* d_out, int out_size, void* d_ws, size_t ws_size,
                              hipStream_t stream)
{
    const float* x    = (const float*)d_in[0];
    const float* emb0 = (const float*)d_in[1];
    const float* emb1 = (const float*)d_in[2];
    float* out        = (float*)d_out;

    unsigned* sbits = (unsigned*)d_ws;                    // 128 KB
    unsigned* res   = (unsigned*)d_ws + SBITS_WORDS;      // 4 MB

    hipMemsetAsync((void*)res, 0, (size_t)RES_WORDS * 4, stream);
    k_bits<<<dim3(4 * 64), dim3(256), 0, stream>>>(x, sbits);
    k_dp2<<<dim3(36, NSEQ), dim3(256), 0, stream>>>(sbits, res);
    k_dec<<<dim3(RES_WORDS / 256), dim3(256), 0, stream>>>(sbits, res, emb0, emb1, out);
}

// Round 4
// 192.622 us; speedup vs baseline: 8.9973x; 1.0472x over previous
//
#include <hip/hip_runtime.h>

// ROSA 1-bit, B=4, T=2048, C=128 (512 sequences).
// Round 4: same i-tiled diagonal DP as round 3 (verified absmax 0), plus:
//  (a) inner per-bit quad forced to 4 VALU via inline asm
//      (v_bfe_i32 / v_add / v_bfi_b32 / v_max_u32) — round-3 codegen was
//      ~7-8 inst/bit (VALU-saturated at 202us vs 94us ideal);
//  (b) res layout transposed to [q][i] (q = b*128+c) so the merge atomics
//      are contiguous per block — WRITE_SIZE 147MB -> ~20MB;
//  (c) k_dec rewritten with LDS transpose (line-covering res reads,
//      coalesced out writes).

#define TT 2048
#define CC 128
#define NW 64
#define NSEQ 512
#define SBITS_WORDS (NSEQ * NW)       // 128 KB
#define RES_WORDS (NSEQ * TT)         // 4 MB, layout [q][i]

// ---------------- kernel 0: pack bits ----------------
__global__ void k_bits(const float* __restrict__ x, unsigned* __restrict__ sbits)
{
    const int b = blockIdx.x >> 6;
    const int w = blockIdx.x & 63;
    const int t = threadIdx.x;
    __shared__ unsigned char sbyt[32 * 132];

    #pragma unroll
    for (int r = 0; r < 16; ++r) {
        const int e  = t + (r << 8);
        const int ii = e >> 7;
        const int c  = e & 127;
        const float v = x[((size_t)(b * TT + (w << 5) + ii)) * CC + c];
        sbyt[ii * 132 + c] = (v > 0.0f) ? 1u : 0u;
    }
    __syncthreads();

    if (t < CC) {
        unsigned word = 0u;
        #pragma unroll
        for (int ii = 0; ii < 32; ++ii)
            word |= (unsigned)(sbyt[ii * 132 + t] & 1u) << ii;
        sbits[((b << 7) | t) * NW + w] = word;
    }
}

// ---------------- kernel 1: tiled diagonal DP ----------------
__global__ __launch_bounds__(256, 4) void k_dp2(
    const unsigned* __restrict__ sbits, unsigned* __restrict__ res)
{
    const int u = blockIdx.x;            // 0..35 (triangular (k, chunk))
    const int q = blockIdx.y;            // sequence = b*128 + c
    int k = 0;
    #pragma unroll
    for (int kk = 1; kk < 8; ++kk) if (u >= (kk * (kk + 1)) / 2) k = kk;
    const int chunk = u - (k * (k + 1)) / 2;
    const int D0 = 1 + (chunk << 8);

    const int tid  = threadIdx.x;
    const int lane = tid & 63;
    const int wv   = tid >> 6;
    const int g    = lane >> 3;          // stream in wave
    const int lm   = lane & 7;           // lane within stream
    const int wloc = (k << 3) + lm;      // fixed output word of this lane
    const int kb   = k << 8;

    __shared__ unsigned pad[128];        // [0..63]=0, [64+w]=word w
    __shared__ unsigned wres[4][8][33];

    if (tid < 64) pad[tid] = 0u;
    else if (tid < 128) pad[tid] = sbits[q * NW + (tid - 64)];
    __syncthreads();

    const unsigned a = pad[64 + wloc];

    unsigned lmax[32];
    #pragma unroll
    for (int bb = 0; bb < 32; ++bb) lmax[bb] = 0u;

    for (int it = 0; it < 8; ++it) {
        const int d  = D0 + (it << 5) + (wv << 3) + g;
        const int dw = d >> 5;
        const int dr = d & 31;
        const unsigned dcode = (unsigned)(TT - d);

        const int s = wloc - dw;
        const unsigned em = (s > 0) ? 0xFFFFFFFFu
                          : ((s == 0) ? (0xFFFFFFFFu << dr) : 0u);

        const unsigned b0 = pad[64 + s];
        const unsigned b1 = pad[63 + s];
        const unsigned sh = dr ? ((b0 << dr) | (b1 >> (32 - dr))) : b0;
        const unsigned m = (~(a ^ sh)) & em;

        // --- boundary incoming run (stream-head lanes, full diagonals) ---
        unsigned inc0 = 0u;
        if (lm == 0 && d < kb) {
            int w = (k << 3) - 1;
            while (w >= 0) {
                const int ss = w - dw;
                const unsigned emw = (ss > 0) ? 0xFFFFFFFFu
                                   : ((ss == 0) ? (0xFFFFFFFFu << dr) : 0u);
                const unsigned c0 = pad[64 + ss];
                const unsigned c1 = pad[63 + ss];
                const unsigned shw = dr ? ((c0 << dr) | (c1 >> (32 - dr))) : c0;
                const unsigned mw = (~(pad[64 + w] ^ shw)) & emw;
                const unsigned t2 = (mw == 0xFFFFFFFFu) ? 32u
                                  : (unsigned)__builtin_clz(~mw);
                inc0 += t2;
                if (t2 < 32u) break;
                --w;
            }
        }

        // --- incoming run per lane ---
        unsigned inc;
        const unsigned long long anyfull = __ballot(m == 0xFFFFFFFFu);
        if (anyfull == 0ULL) {
            const unsigned pm = __shfl_up(m, 1);
            const unsigned lead = (unsigned)__builtin_clz(~pm);
            inc = (lm == 0) ? inc0 : lead;
        } else {
            unsigned gg = (m == 0xFFFFFFFFu) ? 1u : 0u;
            unsigned cc = gg ? 32u : (unsigned)__builtin_clz(~m | 1u);
            #pragma unroll
            for (int st = 1; st < 8; st <<= 1) {
                const unsigned gp = __shfl_up(gg, st);
                const unsigned cp = __shfl_up(cc, st);
                if (lm >= st) { cc += gg ? cp : 0u; gg &= gp; }
            }
            const unsigned h0 = __shfl(inc0, lane & ~7);
            const unsigned outl = cc + (gg ? h0 : 0u);
            const unsigned po = __shfl_up(outl, 1);
            inc = (lm == 0) ? inc0 : po;
        }

        // --- per-bit run + packed max: forced 4 VALU/bit ---
        unsigned pkv = (inc << 11) | dcode;
        #pragma unroll
        for (int bb = 0; bb < 32; ++bb) {
            unsigned keep;
            asm("v_bfe_i32 %0, %3, %4, 1\n\t"
                "v_add_u32 %1, 0x800, %1\n\t"
                "v_bfi_b32 %1, %0, %1, %5\n\t"
                "v_max_u32 %2, %2, %1"
                : "=&v"(keep), "+v"(pkv), "+v"(lmax[bb])
                : "v"(m), "n"(bb), "v"(dcode));
        }
    }

    // --- reduce the 8 streams sharing each word ---
    #pragma unroll
    for (int bb = 0; bb < 32; ++bb) {
        unsigned v = lmax[bb];
        v = max(v, (unsigned)__shfl_xor((int)v, 8));
        v = max(v, (unsigned)__shfl_xor((int)v, 16));
        v = max(v, (unsigned)__shfl_xor((int)v, 32));
        lmax[bb] = v;
    }
    if (lane < 8) {
        #pragma unroll
        for (int bb = 0; bb < 32; ++bb) wres[wv][lane][bb] = lmax[bb];
    }
    __syncthreads();

    // --- block merge + contiguous atomics into res[q][i] ---
    {
        const int lw = tid >> 5, bb = tid & 31;
        const unsigned v = max(max(wres[0][lw][bb], wres[1][lw][bb]),
                               max(wres[2][lw][bb], wres[3][lw][bb]));
        if (v >> 11) {
            const int i = ((k << 3) + lw) * 32 + bb;
            atomicMax(&res[(size_t)q * TT + i], v);
        }
    }
}

// ---------------- kernel 2: decode (LDS transpose) ----------------
// block: (i-tile of 16, b). Phase 1: thread t -> c = t>>1, 8 consecutive i
// (line-covering reads of res[q][i]); phase 2: coalesced out[b][i][c] writes.
__global__ void k_dec(const unsigned* __restrict__ sbits,
                      const unsigned* __restrict__ res,
                      const float* __restrict__ emb0,
                      const float* __restrict__ emb1,
                      float* __restrict__ out)
{
    const int b  = blockIdx.y;
    const int i0 = blockIdx.x << 4;
    const int t  = threadIdx.x;
    __shared__ float trans[16][CC + 4];

    const int c  = t >> 1;
    const int q8 = (t & 1) << 3;
    const unsigned* rp = res + ((size_t)((b << 7) | c) * TT) + i0 + q8;
    const unsigned* bw = sbits + ((size_t)((b << 7) | c)) * NW;
    const float e0 = emb0[c], e1 = emb1[c];

    #pragma unroll
    for (int jj = 0; jj < 8; ++jj) {
        const unsigned v = rp[jj];
        const int i = i0 + q8 + jj;
        float val = 0.0f;
        if (v >> 11) {
            const int d   = TT - (int)(v & 2047u);
            const int e1p = i - d + 1;
            val = ((bw[e1p >> 5] >> (e1p & 31)) & 1u) ? e1 : e0;
        }
        trans[q8 + jj][c] = val;
    }
    __syncthreads();

    const int ii = t >> 4;
    const int c0 = (t & 15) << 3;
    float4 w0 = *(const float4*)&trans[ii][c0];
    float4 w1 = *(const float4*)&trans[ii][c0 + 4];
    float* op = out + ((size_t)(b * TT + i0 + ii)) * CC + c0;
    *(float4*)op       = w0;
    *(float4*)(op + 4) = w1;
}

extern "C" void kernel_launch(void* const* d_in, const int* in_sizes, int n_in,
                              void* d_out, int out_size, void* d_ws, size_t ws_size,
                              hipStream_t stream)
{
    const float* x    = (const float*)d_in[0];
    const float* emb0 = (const float*)d_in[1];
    const float* emb1 = (const float*)d_in[2];
    float* out        = (float*)d_out;

    unsigned* sbits = (unsigned*)d_ws;                    // 128 KB
    unsigned* res   = (unsigned*)d_ws + SBITS_WORDS;      // 4 MB

    hipMemsetAsync((void*)res, 0, (size_t)RES_WORDS * 4, stream);
    k_bits<<<dim3(4 * 64), dim3(256), 0, stream>>>(x, sbits);
    k_dp2<<<dim3(36, NSEQ), dim3(256), 0, stream>>>(sbits, res);
    k_dec<<<dim3(TT / 16, 4), dim3(256), 0, stream>>>(sbits, res, emb0, emb1, out);
}